// Round 1
// baseline (474.700 us; speedup 1.0000x reference)
//
#include <hip/hip_runtime.h>
#include <hip/hip_bf16.h>
#include <cstdint>
#include <cstddef>

#define BB 4
#define NN 1024
#define INDIM 128
#define DD 512
#define HH 8
#define EE 4
#define LL 3
#define HDIM 64

typedef __bf16 bf16x8 __attribute__((ext_vector_type(8)));
typedef float f32x4 __attribute__((ext_vector_type(4)));

__device__ __forceinline__ unsigned short f2b(float f) {
    union { float f; unsigned int u; } v; v.f = f;
    unsigned int u = v.u;
    unsigned int r = (u + 0x7FFFu + ((u >> 16) & 1u)) >> 16;
    return (unsigned short)r;
}

// ---------------- weight transpose+convert: W (K x N fp32) -> Wt (N x K bf16) ---------
__device__ __forceinline__ void transpose_tile_body(const float* __restrict__ src,
                                                    unsigned short* __restrict__ dst,
                                                    int K, int Nc) {
    __shared__ float tl[32][33];
    const int n0 = blockIdx.x * 32, k0 = blockIdx.y * 32;
    const int tx = threadIdx.x, ty = threadIdx.y;
#pragma unroll
    for (int r = 0; r < 4; r++) {
        int k = ty + r * 8;
        tl[k][tx] = src[(size_t)(k0 + k) * Nc + n0 + tx];
    }
    __syncthreads();
#pragma unroll
    for (int r = 0; r < 4; r++) {
        int n = ty + r * 8;
        dst[(size_t)(n0 + n) * K + k0 + tx] = f2b(tl[tx][n]);
    }
}

__global__ void k_transpose_in(const float* __restrict__ w, unsigned short* __restrict__ dst) {
    transpose_tile_body(w, dst, INDIM, DD);
}

__global__ void k_transpose_qkvo(const float* __restrict__ qw, const float* __restrict__ kw,
                                 const float* __restrict__ vw, const float* __restrict__ ow,
                                 unsigned short* __restrict__ dst) {
    int zz = blockIdx.z;
    int l = zz >> 2, tsel = zz & 3;
    const float* src = (tsel == 0) ? qw : (tsel == 1) ? kw : (tsel == 2) ? vw : ow;
    src += (size_t)l * DD * DD;
    transpose_tile_body(src, dst + (size_t)zz * DD * DD, DD, DD);
}

// ---------------- fp32 -> bf16 convert (x) ----------------
__global__ void k_convert(const float* __restrict__ src, unsigned short* __restrict__ dst, int n4) {
    int i = blockIdx.x * blockDim.x + threadIdx.x;
    if (i < n4) {
        float4 v = reinterpret_cast<const float4*>(src)[i];
        uint2 o;
        o.x = (unsigned)f2b(v.x) | ((unsigned)f2b(v.y) << 16);
        o.y = (unsigned)f2b(v.z) | ((unsigned)f2b(v.w) << 16);
        reinterpret_cast<uint2*>(dst)[i] = o;
    }
}

// ---------------- bf16 MFMA GEMM: out[M,512] = A[M,Kd] @ Wt^T + bias (+resid) ---------
// A: M x Kd bf16 row-major. Wt: 512 x Kd bf16 row-major (i.e. W transposed).
// Tile 128x64, 256 threads (4 waves along M, each wave 32 rows x 64 cols).
__global__ __launch_bounds__(256) void k_gemm(
    const unsigned short* __restrict__ A,
    const unsigned short* __restrict__ Wt0, size_t wstride,
    const float* __restrict__ bias0, const float* __restrict__ bias1, const float* __restrict__ bias2,
    float* __restrict__ outf,
    unsigned short* __restrict__ outb, size_t ostride,
    const float* __restrict__ resid,
    int Kd)
{
    __shared__ unsigned short As[128 * 40];
    __shared__ unsigned short Bs[64 * 40];
    const int tid = threadIdx.x;
    const int lane = tid & 63, wv = tid >> 6;
    const int lm = lane & 15, lh = lane >> 4;
    const int m0 = blockIdx.y * 128, n0 = blockIdx.x * 64;
    const int z = blockIdx.z;
    const unsigned short* Wt = Wt0 + (size_t)z * wstride;
    const float* bias = (z == 0) ? bias0 : (z == 1) ? bias1 : bias2;

    f32x4 acc[2][4] = {};

    const int arow = tid >> 1, aseg = tid & 1;
    const int brow = tid >> 2, bseg = tid & 3;
    const unsigned short* ag = A + (size_t)(m0 + arow) * Kd + aseg * 16;
    const unsigned short* bg = Wt + (size_t)(n0 + brow) * Kd + bseg * 8;
    unsigned short* asw = &As[arow * 40 + aseg * 16];
    unsigned short* bsw = &Bs[brow * 40 + bseg * 8];

    for (int k0 = 0; k0 < Kd; k0 += 32) {
        int4 av0 = *reinterpret_cast<const int4*>(ag);
        int4 av1 = *reinterpret_cast<const int4*>(ag + 8);
        int4 bv  = *reinterpret_cast<const int4*>(bg);
        __syncthreads();
        *reinterpret_cast<int4*>(asw) = av0;
        *reinterpret_cast<int4*>(asw + 8) = av1;
        *reinterpret_cast<int4*>(bsw) = bv;
        __syncthreads();
        ag += 32; bg += 32;

        bf16x8 af[2], bfr[4];
#pragma unroll
        for (int ti = 0; ti < 2; ti++)
            af[ti] = *reinterpret_cast<const bf16x8*>(&As[(wv * 32 + ti * 16 + lm) * 40 + lh * 8]);
#pragma unroll
        for (int tj = 0; tj < 4; tj++)
            bfr[tj] = *reinterpret_cast<const bf16x8*>(&Bs[(tj * 16 + lm) * 40 + lh * 8]);
#pragma unroll
        for (int ti = 0; ti < 2; ti++)
#pragma unroll
            for (int tj = 0; tj < 4; tj++)
                acc[ti][tj] = __builtin_amdgcn_mfma_f32_16x16x32_bf16(af[ti], bfr[tj], acc[ti][tj], 0, 0, 0);
    }

#pragma unroll
    for (int ti = 0; ti < 2; ti++) {
#pragma unroll
        for (int tj = 0; tj < 4; tj++) {
#pragma unroll
            for (int r = 0; r < 4; r++) {
                int i = m0 + wv * 32 + ti * 16 + lh * 4 + r;
                int j = n0 + tj * 16 + lm;
                float val = acc[ti][tj][r] + bias[j];
                size_t oidx = (size_t)i * DD + j;
                if (resid) val += resid[oidx];
                if (outf) outf[oidx] = val;
                if (outb) outb[(size_t)z * ostride + oidx] = f2b(val);
            }
        }
    }
}

// ---------------- V transpose: vb (B*N, D) bf16 -> vt (B,H,HD,N) bf16 ----------------
__global__ __launch_bounds__(256) void k_transpose_v(const unsigned short* __restrict__ vb,
                                                     unsigned short* __restrict__ vt) {
    __shared__ unsigned short tl[64 * 72];
    const int bh = blockIdx.x;
    const int b = bh >> 3, h = bh & 7;
    const int n0 = blockIdx.y * 64;
    const int t = threadIdx.x;
    {
        int n = t >> 2, seg = t & 3;
        const unsigned short* src = vb + ((size_t)b * NN + n0 + n) * DD + h * HDIM + seg * 16;
        int4 c0 = *reinterpret_cast<const int4*>(src);
        int4 c1 = *reinterpret_cast<const int4*>(src + 8);
        *reinterpret_cast<int4*>(&tl[n * 72 + seg * 16]) = c0;
        *reinterpret_cast<int4*>(&tl[n * 72 + seg * 16 + 8]) = c1;
    }
    __syncthreads();
    {
        int d = t & 63, nb = t >> 6;
        union { unsigned short s[8]; int4 v; } pk0, pk1;
#pragma unroll
        for (int q = 0; q < 8; q++) pk0.s[q] = tl[(nb * 16 + q) * 72 + d];
#pragma unroll
        for (int q = 0; q < 8; q++) pk1.s[q] = tl[(nb * 16 + 8 + q) * 72 + d];
        unsigned short* dst = vt + (((size_t)b * HH + h) * HDIM + d) * NN + n0 + nb * 16;
        *reinterpret_cast<int4*>(dst) = pk0.v;
        *reinterpret_cast<int4*>(dst + 8) = pk1.v;
    }
}

// ---------------- fused attention (flash-style, one block per (b, 16-row i-tile)) -----
// 8 waves = 8 heads. Q frags in regs; K,V read direct from global (L2-resident);
// edges tile staged in LDS (shared by all heads); P bounced via per-wave LDS for PV.
__global__ __launch_bounds__(512) void k_attn(
    const unsigned short* __restrict__ qb,
    const unsigned short* __restrict__ kb,
    const unsigned short* __restrict__ vt,
    const float* __restrict__ edges,
    const float* __restrict__ ew,     // (L,E,H)
    const float* __restrict__ ebias,  // (L,H)
    int layer,
    unsigned short* __restrict__ attnob)
{
    __shared__ float e_lds[16 * 64 * EE];         // 16 KB
    __shared__ unsigned short p_lds[HH][16 * 72]; // 18 KB
    const int b = blockIdx.y;
    const int i0 = blockIdx.x * 16;
    const int tid = threadIdx.x;
    const int lane = tid & 63, h = tid >> 6;
    const int lm = lane & 15, lh = lane >> 4;

    const float ew0 = ew[(layer * EE + 0) * HH + h];
    const float ew1 = ew[(layer * EE + 1) * HH + h];
    const float ew2 = ew[(layer * EE + 2) * HH + h];
    const float ew3 = ew[(layer * EE + 3) * HH + h];
    const float ebh = ebias[layer * HH + h];

    const unsigned short* qrow = qb + ((size_t)(b * NN) + i0 + lm) * DD + h * HDIM + lh * 8;
    const bf16x8 aq0 = *reinterpret_cast<const bf16x8*>(qrow);
    const bf16x8 aq1 = *reinterpret_cast<const bf16x8*>(qrow + 32);

    f32x4 acc[4] = {};
    float mrow[4], lrow[4];
#pragma unroll
    for (int r = 0; r < 4; r++) { mrow[r] = -1e30f; lrow[r] = 0.f; }

    for (int j0 = 0; j0 < NN; j0 += 64) {
        __syncthreads();
#pragma unroll
        for (int p = 0; p < 2; p++) {
            int c = p * 512 + tid;
            int ii = c >> 6, jj = c & 63;
            *reinterpret_cast<float4*>(&e_lds[c * 4]) =
                *reinterpret_cast<const float4*>(&edges[(((size_t)b * NN + i0 + ii) * NN + j0 + jj) * EE]);
        }
        __syncthreads();

        // QK^T for 4 j-subtiles of 16
        f32x4 s[4];
#pragma unroll
        for (int jt = 0; jt < 4; jt++) {
            const unsigned short* krow = kb + ((size_t)(b * NN) + j0 + jt * 16 + lm) * DD + h * HDIM + lh * 8;
            bf16x8 bk0 = *reinterpret_cast<const bf16x8*>(krow);
            bf16x8 bk1 = *reinterpret_cast<const bf16x8*>(krow + 32);
            f32x4 t = {};
            t = __builtin_amdgcn_mfma_f32_16x16x32_bf16(aq0, bk0, t, 0, 0, 0);
            t = __builtin_amdgcn_mfma_f32_16x16x32_bf16(aq1, bk1, t, 0, 0, 0);
            s[jt] = t;
        }

        // bias + scale + online softmax (rows i = 4*lh + r, cols j = jt*16 + lm)
        float pval[4][4];
        float corr[4];
#pragma unroll
        for (int r = 0; r < 4; r++) {
            int ii = lh * 4 + r;
            float mt = -1e30f;
#pragma unroll
            for (int jt = 0; jt < 4; jt++) {
                int jj = jt * 16 + lm;
                const float4 ev = *reinterpret_cast<const float4*>(&e_lds[(ii * 64 + jj) * 4]);
                float sv = s[jt][r] * 0.125f + ev.x * ew0 + ev.y * ew1 + ev.z * ew2 + ev.w * ew3 + ebh;
                pval[r][jt] = sv;
                mt = fmaxf(mt, sv);
            }
            mt = fmaxf(mt, __shfl_xor(mt, 1));
            mt = fmaxf(mt, __shfl_xor(mt, 2));
            mt = fmaxf(mt, __shfl_xor(mt, 4));
            mt = fmaxf(mt, __shfl_xor(mt, 8));
            float mn = fmaxf(mrow[r], mt);
            corr[r] = __expf(mrow[r] - mn);
            mrow[r] = mn;
            float ls = 0.f;
#pragma unroll
            for (int jt = 0; jt < 4; jt++) {
                float pv = __expf(pval[r][jt] - mn);
                pval[r][jt] = pv;
                ls += pv;
            }
            ls += __shfl_xor(ls, 1);
            ls += __shfl_xor(ls, 2);
            ls += __shfl_xor(ls, 4);
            ls += __shfl_xor(ls, 8);
            lrow[r] = lrow[r] * corr[r] + ls;
#pragma unroll
            for (int jt = 0; jt < 4; jt++)
                p_lds[h][ii * 72 + jt * 16 + lm] = f2b(pval[r][jt]);
        }
#pragma unroll
        for (int dt = 0; dt < 4; dt++)
#pragma unroll
            for (int r = 0; r < 4; r++) acc[dt][r] *= corr[r];

        // PV: A = P tile (16 x 64 from LDS), B = Vt rows (d-major, contiguous in j)
#pragma unroll
        for (int kc = 0; kc < 2; kc++) {
            bf16x8 ap = *reinterpret_cast<const bf16x8*>(&p_lds[h][lm * 72 + kc * 32 + lh * 8]);
#pragma unroll
            for (int dt = 0; dt < 4; dt++) {
                const unsigned short* vrow =
                    vt + (((size_t)(b * HH) + h) * HDIM + dt * 16 + lm) * NN + j0 + kc * 32 + lh * 8;
                bf16x8 bv = *reinterpret_cast<const bf16x8*>(vrow);
                acc[dt] = __builtin_amdgcn_mfma_f32_16x16x32_bf16(ap, bv, acc[dt], 0, 0, 0);
            }
        }
    }

#pragma unroll
    for (int dt = 0; dt < 4; dt++) {
#pragma unroll
        for (int r = 0; r < 4; r++) {
            float val = acc[dt][r] / lrow[r];
            attnob[((size_t)(b * NN) + i0 + lh * 4 + r) * DD + h * HDIM + dt * 16 + lm] = f2b(val);
        }
    }
}

// ---------------- final layernorm: one wave per row ----------------
__global__ __launch_bounds__(64) void k_ln(const float* __restrict__ hbuf,
                                           const float* __restrict__ g,
                                           const float* __restrict__ bta,
                                           float* __restrict__ out) {
    const int row = blockIdx.x;
    const int lane = threadIdx.x;
    const float* hr = hbuf + (size_t)row * DD;
    float4 v0 = reinterpret_cast<const float4*>(hr)[lane * 2];
    float4 v1 = reinterpret_cast<const float4*>(hr)[lane * 2 + 1];
    float vals[8] = {v0.x, v0.y, v0.z, v0.w, v1.x, v1.y, v1.z, v1.w};
    float sum = 0.f, sq = 0.f;
#pragma unroll
    for (int q = 0; q < 8; q++) { sum += vals[q]; sq += vals[q] * vals[q]; }
#pragma unroll
    for (int m = 1; m <= 32; m <<= 1) {
        sum += __shfl_xor(sum, m);
        sq += __shfl_xor(sq, m);
    }
    float mu = sum * (1.f / DD);
    float var = sq * (1.f / DD) - mu * mu;
    float rs = rsqrtf(var + 1e-5f);
    const float* gp = g + lane * 8;
    const float* bp = bta + lane * 8;
    float* op = out + (size_t)row * DD + lane * 8;
#pragma unroll
    for (int q = 0; q < 8; q++) op[q] = (vals[q] - mu) * rs * gp[q] + bp[q];
}

extern "C" void kernel_launch(void* const* d_in, const int* in_sizes, int n_in,
                              void* d_out, int out_size, void* d_ws, size_t ws_size,
                              hipStream_t stream) {
    (void)in_sizes; (void)n_in; (void)out_size; (void)ws_size;
    const float* x     = (const float*)d_in[0];
    const float* edges = (const float*)d_in[1];
    const float* in_w  = (const float*)d_in[2];
    const float* in_b  = (const float*)d_in[3];
    const float* qw    = (const float*)d_in[4];
    const float* qbias = (const float*)d_in[5];
    const float* kw    = (const float*)d_in[6];
    const float* kbias = (const float*)d_in[7];
    const float* vw    = (const float*)d_in[8];
    const float* vbias = (const float*)d_in[9];
    const float* ow    = (const float*)d_in[10];
    const float* obias = (const float*)d_in[11];
    const float* ew    = (const float*)d_in[12];
    const float* ebias = (const float*)d_in[13];
    const float* ln_g  = (const float*)d_in[14];
    const float* ln_b  = (const float*)d_in[15];
    float* out = (float*)d_out;

    char* ws = (char*)d_ws;
    size_t off = 0;
    auto alloc = [&](size_t bytes) -> void* {
        void* p = ws + off;
        off += (bytes + 255) & ~(size_t)255;
        return p;
    };
    const size_t M = (size_t)BB * NN;            // 4096
    float*          hbuf  = (float*)         alloc(M * DD * 4);
    unsigned short* hb    = (unsigned short*)alloc(M * DD * 2);
    unsigned short* xb    = (unsigned short*)alloc(M * INDIM * 2);
    unsigned short* wt_in = (unsigned short*)alloc((size_t)DD * INDIM * 2);
    unsigned short* wt    = (unsigned short*)alloc((size_t)12 * DD * DD * 2);
    unsigned short* qkvb  = (unsigned short*)alloc((size_t)3 * M * DD * 2);
    unsigned short* vtb   = (unsigned short*)alloc(M * DD * 2);
    unsigned short* attnob= (unsigned short*)alloc(M * DD * 2);
    const size_t BND = M * DD;

    // weight prep
    k_transpose_in<<<dim3(DD / 32, INDIM / 32), dim3(32, 8), 0, stream>>>(in_w, wt_in);
    k_transpose_qkvo<<<dim3(DD / 32, DD / 32, 12), dim3(32, 8), 0, stream>>>(qw, kw, vw, ow, wt);
    k_convert<<<dim3(512), dim3(256), 0, stream>>>(x, xb, (int)(M * INDIM / 4));

    // input projection: h = x @ in_w + in_b  (writes fp32 h and bf16 hb)
    k_gemm<<<dim3(8, 32, 1), dim3(256), 0, stream>>>(
        xb, wt_in, (size_t)0, in_b, in_b, in_b, hbuf, hb, (size_t)0, (const float*)nullptr, INDIM);

    for (int l = 0; l < LL; l++) {
        // q,k,v projections in one z-batched launch (bf16 outputs)
        k_gemm<<<dim3(8, 32, 3), dim3(256), 0, stream>>>(
            hb, wt + (size_t)(l * 4) * DD * DD, (size_t)DD * DD,
            qbias + l * DD, kbias + l * DD, vbias + l * DD,
            (float*)nullptr, qkvb, BND, (const float*)nullptr, DD);
        // V -> V^T (B,H,HD,N)
        k_transpose_v<<<dim3(32, 16), dim3(256), 0, stream>>>(qkvb + 2 * BND, vtb);
        // fused attention -> attnob (bf16)
        k_attn<<<dim3(64, 4), dim3(512), 0, stream>>>(
            qkvb, qkvb + BND, vtb, edges, ew, ebias, l, attnob);
        // output projection + residual: h = h + attno @ ow + ob (writes h fp32 + hb bf16)
        k_gemm<<<dim3(8, 32, 1), dim3(256), 0, stream>>>(
            attnob, wt + (size_t)(l * 4 + 3) * DD * DD, (size_t)0,
            obias + l * DD, obias + l * DD, obias + l * DD,
            hbuf, hb, (size_t)0, hbuf, DD);
    }

    k_ln<<<dim3((unsigned)M), dim3(64), 0, stream>>>(hbuf, ln_g, ln_b, out);
}